// Round 7
// baseline (6483.424 us; speedup 1.0000x reference)
//
#include <hip/hip_runtime.h>

// LSTM T=4096, IN=32, H=512, OUT=32, 3 layers + projection.
// R20 = R17 + ownB second own-copy ONLY (R19's fused GEMM dropped).
//   R19 post-mortem: bundle (ownB + fused polling GEMM) = +3.8%. The GEMM's
//   staging verify-loads hit L2's ownA lines right behind the producing
//   front — the hot-line reader load R12/R18 proved harmful. ownB itself
//   follows the ONLY verified-positive mechanism (reader removal from hot
//   lines, R17: 64->32 readers = -1.5%) and was never isolated. R20 tests
//   it cleanly: own-line fan-out 32->16 wave-pollers/line.
//   ownB ring mbB[layer][t&1][512]: wave-0 lanes 16-31 store a second
//   own-copy; WGs g<16 poll ownA (full history), g>=16 poll the ring.
//   Ring overwrite safety is pure program/barrier order: producer publishes
//   h(t+2) into slot s=t&1 only after observing ALL 512 cols of h(t+1),
//   which requires every WG's publish of t+1, which follows that WG's
//   own-poller reads of slot s at step t+1. No timing assumptions.
//   Falsification (>=6200): revert to exact R17 next round; floor declared.
// Protocol invariants (R3-R19):
//   - packed u64 {seq-tag:32 | value:32}: the flag IS the data;
//   - relaxed agent-scope atomics only, NO cache-wide fences;
//   - <=64 weight floats/lane, loop-constant indexing;
//   - publish = ONE wave, full 128B lines (ownA / ownB-ring / prevX);
//   - 1-deep RTT-paced polling (R12/R18: denser ALWAYS loses);
//   - no trailing readers near the producing front (R19);
//   - per-wave poll straight into VGPRs, readlane-broadcast dot;
//   - ONE s_barrier per step, part[] double-buffered;
//   - partial reduction = wave-0 LDS reads (R11/R15: alternatives lose).

#define T_SEQ 4096
#define HDIM  512
#define NWG_L 32
#define NTH   1024

typedef unsigned long long u64;

__device__ __forceinline__ u64 cohLoad(const u64* p) {
    return __hip_atomic_load(p, __ATOMIC_RELAXED, __HIP_MEMORY_SCOPE_AGENT);
}
__device__ __forceinline__ void cohStore(u64* p, u64 v) {
    __hip_atomic_store(p, v, __ATOMIC_RELAXED, __HIP_MEMORY_SCOPE_AGENT);
}
__device__ __forceinline__ float fsigmoid(float x) {
    return __builtin_amdgcn_rcpf(1.f + __expf(-x));
}
__device__ __forceinline__ float ftanh(float x) {
    float e = __expf(2.f * fabsf(x));           // +inf ok -> t = 1
    float t = 1.f - 2.f * __builtin_amdgcn_rcpf(e + 1.f);
    return copysignf(t, x);
}
__device__ __forceinline__ float bcast(float v, int k) {
    return __uint_as_float(__builtin_amdgcn_readlane(__float_as_uint(v), k));
}

// ---------------------------------------------------------------------------
// Tiled fp32 GEMM (final projection): C[M][N] = A[M][K] * B[N][K]^T + bias[n]
// ---------------------------------------------------------------------------
template <int BM, int BN, int BK>
__global__ __launch_bounds__(256)
void gemm_abt(const float* __restrict__ A, const float* __restrict__ B,
              const float* __restrict__ bias1,
              float* __restrict__ C, int M, int N, int K) {
    constexpr int NTX = BN / 4;
    constexpr int NTY = 256 / NTX;
    constexpr int TM  = BM / NTY;
    __shared__ float As[BM][BK + 1];
    __shared__ float Bs[BN][BK + 1];

    const int tid = threadIdx.x;
    const int tx = tid % NTX;
    const int ty = tid / NTX;
    const int m0 = blockIdx.y * BM;
    const int n0 = blockIdx.x * BN;

    float acc[TM][4];
    #pragma unroll
    for (int i = 0; i < TM; ++i)
        #pragma unroll
        for (int j = 0; j < 4; ++j) acc[i][j] = 0.f;

    for (int k0 = 0; k0 < K; k0 += BK) {
        constexpr int AV = BM * BK / 4;
        #pragma unroll
        for (int i = tid; i < AV; i += 256) {
            int r = i / (BK / 4), c4 = i % (BK / 4);
            float4 v = *(const float4*)(A + (size_t)(m0 + r) * K + k0 + c4 * 4);
            As[r][c4 * 4 + 0] = v.x; As[r][c4 * 4 + 1] = v.y;
            As[r][c4 * 4 + 2] = v.z; As[r][c4 * 4 + 3] = v.w;
        }
        constexpr int BV = BN * BK / 4;
        #pragma unroll
        for (int i = tid; i < BV; i += 256) {
            int r = i / (BK / 4), c4 = i % (BK / 4);
            float4 v = *(const float4*)(B + (size_t)(n0 + r) * K + k0 + c4 * 4);
            Bs[r][c4 * 4 + 0] = v.x; Bs[r][c4 * 4 + 1] = v.y;
            Bs[r][c4 * 4 + 2] = v.z; Bs[r][c4 * 4 + 3] = v.w;
        }
        __syncthreads();
        #pragma unroll
        for (int kk = 0; kk < BK; ++kk) {
            float a[TM], b[4];
            #pragma unroll
            for (int i = 0; i < TM; ++i) a[i] = As[ty * TM + i][kk];
            #pragma unroll
            for (int j = 0; j < 4; ++j) b[j] = Bs[tx * 4 + j][kk];
            #pragma unroll
            for (int i = 0; i < TM; ++i)
                #pragma unroll
                for (int j = 0; j < 4; ++j) acc[i][j] += a[i] * b[j];
        }
        __syncthreads();
    }

    #pragma unroll
    for (int j = 0; j < 4; ++j) {
        float bv = bias1 ? bias1[n0 + tx * 4 + j] : 0.f;
        #pragma unroll
        for (int i = 0; i < TM; ++i) acc[i][j] += bv;
    }
    #pragma unroll
    for (int i = 0; i < TM; ++i) {
        int m = m0 + ty * TM + i;
        float4 v = make_float4(acc[i][0], acc[i][1], acc[i][2], acc[i][3]);
        *(float4*)(C + (size_t)m * N + n0 + tx * 4) = v;
    }
}

// ---------------------------------------------------------------------------
__global__ void unpack_h(const u64* __restrict__ hp, float* __restrict__ out,
                         int n) {
    int i = blockIdx.x * blockDim.x + threadIdx.x;
    if (i < n) out[i] = __uint_as_float((unsigned)hp[i]);
}

// ---------------------------------------------------------------------------
// 32 WGs/layer x 1024 thr (16 waves). Lane = row (gate*16 + col_local).
// Layers 1/2: wave wv owns k-chunk [wv*64,+64) of concat [prev-h; own-h]:
//   wv<8 -> prev-h / Wih (poll hpX prev-feed copy),
//   wv>=8 -> own-h / Whh (poll ownA if g<16, else ownB ring).
// Layer 0: wave wv owns own-h k [wv*32,+32) (lanes 0-31 poll) and x k
//   [2wv,2wv+1] (lanes 32-33 load seq; weights in w[32..33]).
// Publish: wave 0, all lanes compute gates redundantly (c replicated per
//   16-lane group); lanes 0-15 store ownA, 16-31 store ownB ring slot t&1,
//   32-47 store prevX (layers 0-1) — three 128B lines, one wave.
// ---------------------------------------------------------------------------
__global__ __launch_bounds__(NTH, 4)
void lstm_fused(const float* __restrict__ seq,
                const float* __restrict__ Wih1, const float* __restrict__ Whh1,
                const float* __restrict__ bih1, const float* __restrict__ bhh1,
                const float* __restrict__ Wih2, const float* __restrict__ Whh2,
                const float* __restrict__ bih2, const float* __restrict__ bhh2,
                const float* __restrict__ Wih3, const float* __restrict__ Whh3,
                const float* __restrict__ bih3, const float* __restrict__ bhh3,
                u64* __restrict__ hp) {
    __shared__ float part[2][NTH];      // [pb][wv*64 + row]

    const int blk   = blockIdx.x;
    const int layer = blk >> 5;
    const int g     = blk & 31;
    const int tid   = threadIdx.x;
    const int wv    = tid >> 6;          // 0..15
    const int lane  = tid & 63;          // = row (gate*16 + col_local)
    const int grow  = (lane >> 4) * HDIM + g * 16 + (lane & 15);

    const float* Wih = layer == 0 ? Wih1 : (layer == 1 ? Wih2 : Wih3);
    const float* Whh = layer == 0 ? Whh1 : (layer == 1 ? Whh2 : Whh3);
    const float* bih = layer == 0 ? bih1 : (layer == 1 ? bih2 : bih3);
    const float* bhh = layer == 0 ? bhh1 : (layer == 1 ? bhh2 : bhh3);

    // ---- 64 weight floats/lane (loop-constant indexing only) ----
    float w[64];
    #pragma unroll
    for (int m = 0; m < 64; ++m) w[m] = 0.f;
    if (layer == 0) {
        const float* wp = Whh + (size_t)grow * HDIM + wv * 32;
        #pragma unroll
        for (int i = 0; i < 8; ++i) {
            float4 v = ((const float4*)wp)[i];
            w[4*i+0]=v.x; w[4*i+1]=v.y; w[4*i+2]=v.z; w[4*i+3]=v.w;
        }
        // x weights: 2 per wave (k = 2wv, 2wv+1), all 16 waves balanced.
        w[32] = Wih[(size_t)grow * 32 + 2 * wv + 0];
        w[33] = Wih[(size_t)grow * 32 + 2 * wv + 1];
    } else {
        const float* wp = (wv < 8)
            ? Wih + (size_t)grow * HDIM + wv * 64
            : Whh + (size_t)grow * HDIM + (wv - 8) * 64;
        #pragma unroll
        for (int i = 0; i < 16; ++i) {
            float4 v = ((const float4*)wp)[i];
            w[4*i+0]=v.x; w[4*i+1]=v.y; w[4*i+2]=v.z; w[4*i+3]=v.w;
        }
    }
    #pragma unroll
    for (int m = 0; m < 64; ++m) asm volatile("" : "+v"(w[m]));

    const float brow = bih[grow] + bhh[grow];

    // hp layout (u64): [0..3)T*H ownA | [3..5)T*H prevX(L0,L1) | mbB[3][2][H]
    u64*       hpOwn   = hp + (size_t)layer * T_SEQ * HDIM;
    u64*       hpX     = hp + (size_t)3 * T_SEQ * HDIM;
    u64*       hpXOwn  = hpX + (size_t)layer * T_SEQ * HDIM;        // L0/L1
    const u64* hpPrevX = hpX + (size_t)(layer > 0 ? layer - 1 : 0) * T_SEQ * HDIM;
    u64*       mbOwn   = hp + (size_t)5 * T_SEQ * HDIM
                            + (size_t)layer * 2 * HDIM;   // 2-deep own ring

    // Own-pollers read copy A (g<16) or copy B ring (g>=16):
    // per-line own fan-out = 16 wave-pollers (was 32 in R17, 64 pre-R17).
    const bool useB = (g >= 16);

    float c = 0.f;   // cell state (wave 0, replicated per 16-lane group)

    for (unsigned t = 0; t < T_SEQ; ++t) {
        const int pb = t & 1;

        // ---- per-wave poll: chunk element straight into a VGPR ----
        float hval = 0.f;
        float xval = 0.f;
        if (layer == 0) {
            if (lane < 32 && t > 0) {
                const u64* ph = useB
                    ? mbOwn + (size_t)((t - 1) & 1) * HDIM + wv * 32 + lane
                    : hpOwn + (size_t)(t - 1) * HDIM + wv * 32 + lane;
                u64 v;
                do { v = cohLoad(ph); } while ((unsigned)(v >> 32) != t);
                hval = __uint_as_float((unsigned)v);
            }
            if (lane >= 32 && lane < 34)     // x: 2 elements per wave
                xval = seq[(size_t)t * 32 + 2 * wv + (lane - 32)];
        } else {
            if (wv < 8) {              // prev-layer h[t] via prev-feed copy
                const u64* px = hpPrevX + (size_t)t * HDIM + wv * 64 + lane;
                u64 v;
                do { v = cohLoad(px); } while ((unsigned)(v >> 32) != t + 1u);
                hval = __uint_as_float((unsigned)v);
            } else if (t > 0) {        // own h[t-1], tag t
                const u64* ph = useB
                    ? mbOwn + (size_t)((t - 1) & 1) * HDIM + (wv - 8) * 64 + lane
                    : hpOwn + (size_t)(t - 1) * HDIM + (wv - 8) * 64 + lane;
                u64 v;
                do { v = cohLoad(ph); } while ((unsigned)(v >> 32) != t);
                hval = __uint_as_float((unsigned)v);
            }
        }

        // ---- dot: readlane broadcast + fmac, NO LDS ----
        float pe = 0.f, po = 0.f;
        if (layer == 0) {
            #pragma unroll
            for (int k = 0; k < 32; k += 2) {
                pe = fmaf(bcast(hval, k),     w[k],     pe);
                po = fmaf(bcast(hval, k + 1), w[k + 1], po);
            }
            // balanced x contribution: 2 MACs per wave
            pe = fmaf(bcast(xval, 32), w[32], pe);
            po = fmaf(bcast(xval, 33), w[33], po);
        } else {
            #pragma unroll
            for (int k = 0; k < 64; k += 2) {
                pe = fmaf(bcast(hval, k),     w[k],     pe);
                po = fmaf(bcast(hval, k + 1), w[k + 1], po);
            }
        }
        part[pb][wv * 64 + lane] = pe + po;
        __syncthreads();

        // ---- wave 0: cross-wave sum, gates, triple-copy 128B publishes ----
        if (wv == 0) {
            float tot = brow;
            #pragma unroll
            for (int wvv = 0; wvv < 16; ++wvv) tot += part[pb][wvv * 64 + lane];
            const int c16 = lane & 15;
            float ai = __shfl(tot, c16 +  0, 64);
            float af = __shfl(tot, c16 + 16, 64);
            float ag = __shfl(tot, c16 + 32, 64);
            float ao = __shfl(tot, c16 + 48, 64);
            float iv = fsigmoid(ai);
            float fv = fsigmoid(af);
            float gv = ftanh(ag);
            float ov = fsigmoid(ao);
            c = fv * c + iv * gv;            // replicated per 16-lane group
            float h = ov * ftanh(c);
            u64 pkt = (u64)__float_as_uint(h) | ((u64)(t + 1u) << 32);
            if (lane < 16)                   // ownA: WGs g<16 + extraction
                cohStore(hpOwn + (size_t)t * HDIM + g * 16 + lane, pkt);
            else if (lane < 32)              // ownB ring: WGs g>=16
                cohStore(mbOwn + (size_t)(t & 1) * HDIM + g * 16 + (lane - 16),
                         pkt);
            else if (lane < 48 && layer < 2) // prev-feed: next layer only
                cohStore(hpXOwn + (size_t)t * HDIM + g * 16 + (lane - 32),
                         pkt);
        }
        // Other waves roll straight into polling t+1 (no pre-dot barrier:
        // each wave consumes only its own polled registers). part[] is
        // double-buffered; writes to part[pb] recur only at t+2, after
        // barrier(t+1), which wave 0 reaches only after its tail(t) reads.
        // mbOwn slot s overwrite (t+2) is ordered after all slot-s reads
        // (chain in header comment).
    }
}

// ---------------------------------------------------------------------------
extern "C" void kernel_launch(void* const* d_in, const int* in_sizes, int n_in,
                              void* d_out, int out_size, void* d_ws, size_t ws_size,
                              hipStream_t stream) {
    const float* seq   = (const float*)d_in[0];
    const float* W_ih1 = (const float*)d_in[1];
    const float* W_hh1 = (const float*)d_in[2];
    const float* b_ih1 = (const float*)d_in[3];
    const float* b_hh1 = (const float*)d_in[4];
    const float* W_ih2 = (const float*)d_in[5];
    const float* W_hh2 = (const float*)d_in[6];
    const float* b_ih2 = (const float*)d_in[7];
    const float* b_hh2 = (const float*)d_in[8];
    const float* W_ih3 = (const float*)d_in[9];
    const float* W_hh3 = (const float*)d_in[10];
    const float* b_ih3 = (const float*)d_in[11];
    const float* b_hh3 = (const float*)d_in[12];
    const float* W_out = (const float*)d_in[13];
    const float* b_out = (const float*)d_in[14];
    float* out = (float*)d_out;

    // Workspace (u64): ownA[3][T][512] (50.3MB) + prevX[2][T][512] (33.5MB)
    // + mbB[3][2][512] ring (24KB); hs2 floats reuse the dead layer-0
    // packed region after the recurrence.
    u64*   hp   = (u64*)d_ws;
    float* hs2f = (float*)d_ws;
    const u64* hp2 = hp + (size_t)2 * T_SEQ * HDIM;

    const size_t WS_U64 = (size_t)5 * T_SEQ * HDIM + (size_t)3 * 2 * HDIM;
    hipMemsetAsync(hp, 0, WS_U64 * sizeof(u64), stream);

    lstm_fused<<<3 * NWG_L, NTH, 0, stream>>>(
        seq, W_ih1, W_hh1, b_ih1, b_hh1, W_ih2, W_hh2, b_ih2, b_hh2,
        W_ih3, W_hh3, b_ih3, b_hh3, hp);

    const int n = T_SEQ * HDIM;
    unpack_h<<<(n + 255) / 256, 256, 0, stream>>>(hp2, hs2f, n);

    gemm_abt<64, 32, 32><<<dim3(1, T_SEQ / 64), 256, 0, stream>>>(
        hs2f, W_out, b_out, out, T_SEQ, 32, HDIM);
}

// Round 8
// 6170.335 us; speedup vs baseline: 1.0507x; 1.0507x over previous
//
#include <hip/hip_runtime.h>

// LSTM T=4096, IN=32, H=512, OUT=32, 3 layers + projection.
// R21 = byte-exact revert to R17, the measured session optimum (6164us).
//   R20 post-mortem: ownB slot-reused ring +6.5% (FETCH 532->740MB): 2-deep
//   slot reuse makes relief lines bounce writer-exclusive <-> 16-reader-
//   shared every other step -> recurring MALL coherence re-fetches.
//   Reader-removal helps ONLY with write-once relief lines (R17 -1.5%).
// Complete falsified-gradient map around this structure:
//   poll density x2 (R12 +15%, R18 +8%) | redundant publish (R14 +21%) |
//   LDS-dot repartition (R8/R9 +80-120%) | LDS-atomic reduce (R15 +51%) |
//   barrier removal (R11 +21%) | slot-reused 2nd copy (R20 +6.5%) |
//   trailing fused readers (R19 +3.8%) | L0 balance (R16 neutral, kept) |
//   write-once dual copy (R17 -1.5%, kept).
// Structure: step ~1.49us ~3580cyc = store->MALL visibility + poll-phase
//   quantization + RTT + dot issue (16wv x 128 VALU / 4 SIMD) + barrier +
//   tail + 32-publisher max-coupling. Latency-bound floor: HBM 1.3%,
//   VALU 15%, MfmaUtil 0, conflicts 0 — no classical roofline applies;
//   h (512-wide) must make an all-to-all hop through the MALL (the only
//   XCD-coherent point; G16 forbids same-XCD placement assumptions) every
//   one of 4096 strictly-serial steps.
// Protocol invariants (R3-R20):
//   - packed u64 {seq-tag:32 | value:32}: the flag IS the data;
//   - relaxed agent-scope atomics only, NO cache-wide fences;
//   - <=64 weight floats/lane, loop-constant indexing;
//   - publish = ONE wave, full 128B WRITE-ONCE lines (ownA + prevX);
//   - 1-deep RTT-paced polling; no extra readers near the front;
//   - per-wave poll straight into VGPRs, readlane-broadcast dot;
//   - ONE s_barrier per step, part[] double-buffered;
//   - partial reduction = wave-0 LDS reads.

#define T_SEQ 4096
#define HDIM  512
#define NWG_L 32
#define NTH   1024

typedef unsigned long long u64;

__device__ __forceinline__ u64 cohLoad(const u64* p) {
    return __hip_atomic_load(p, __ATOMIC_RELAXED, __HIP_MEMORY_SCOPE_AGENT);
}
__device__ __forceinline__ void cohStore(u64* p, u64 v) {
    __hip_atomic_store(p, v, __ATOMIC_RELAXED, __HIP_MEMORY_SCOPE_AGENT);
}
__device__ __forceinline__ float fsigmoid(float x) {
    return __builtin_amdgcn_rcpf(1.f + __expf(-x));
}
__device__ __forceinline__ float ftanh(float x) {
    float e = __expf(2.f * fabsf(x));           // +inf ok -> t = 1
    float t = 1.f - 2.f * __builtin_amdgcn_rcpf(e + 1.f);
    return copysignf(t, x);
}
__device__ __forceinline__ float bcast(float v, int k) {
    return __uint_as_float(__builtin_amdgcn_readlane(__float_as_uint(v), k));
}

// ---------------------------------------------------------------------------
// Tiled fp32 GEMM (final projection): C[M][N] = A[M][K] * B[N][K]^T + bias[n]
// ---------------------------------------------------------------------------
template <int BM, int BN, int BK>
__global__ __launch_bounds__(256)
void gemm_abt(const float* __restrict__ A, const float* __restrict__ B,
              const float* __restrict__ bias1,
              float* __restrict__ C, int M, int N, int K) {
    constexpr int NTX = BN / 4;
    constexpr int NTY = 256 / NTX;
    constexpr int TM  = BM / NTY;
    __shared__ float As[BM][BK + 1];
    __shared__ float Bs[BN][BK + 1];

    const int tid = threadIdx.x;
    const int tx = tid % NTX;
    const int ty = tid / NTX;
    const int m0 = blockIdx.y * BM;
    const int n0 = blockIdx.x * BN;

    float acc[TM][4];
    #pragma unroll
    for (int i = 0; i < TM; ++i)
        #pragma unroll
        for (int j = 0; j < 4; ++j) acc[i][j] = 0.f;

    for (int k0 = 0; k0 < K; k0 += BK) {
        constexpr int AV = BM * BK / 4;
        #pragma unroll
        for (int i = tid; i < AV; i += 256) {
            int r = i / (BK / 4), c4 = i % (BK / 4);
            float4 v = *(const float4*)(A + (size_t)(m0 + r) * K + k0 + c4 * 4);
            As[r][c4 * 4 + 0] = v.x; As[r][c4 * 4 + 1] = v.y;
            As[r][c4 * 4 + 2] = v.z; As[r][c4 * 4 + 3] = v.w;
        }
        constexpr int BV = BN * BK / 4;
        #pragma unroll
        for (int i = tid; i < BV; i += 256) {
            int r = i / (BK / 4), c4 = i % (BK / 4);
            float4 v = *(const float4*)(B + (size_t)(n0 + r) * K + k0 + c4 * 4);
            Bs[r][c4 * 4 + 0] = v.x; Bs[r][c4 * 4 + 1] = v.y;
            Bs[r][c4 * 4 + 2] = v.z; Bs[r][c4 * 4 + 3] = v.w;
        }
        __syncthreads();
        #pragma unroll
        for (int kk = 0; kk < BK; ++kk) {
            float a[TM], b[4];
            #pragma unroll
            for (int i = 0; i < TM; ++i) a[i] = As[ty * TM + i][kk];
            #pragma unroll
            for (int j = 0; j < 4; ++j) b[j] = Bs[tx * 4 + j][kk];
            #pragma unroll
            for (int i = 0; i < TM; ++i)
                #pragma unroll
                for (int j = 0; j < 4; ++j) acc[i][j] += a[i] * b[j];
        }
        __syncthreads();
    }

    #pragma unroll
    for (int j = 0; j < 4; ++j) {
        float bv = bias1 ? bias1[n0 + tx * 4 + j] : 0.f;
        #pragma unroll
        for (int i = 0; i < TM; ++i) acc[i][j] += bv;
    }
    #pragma unroll
    for (int i = 0; i < TM; ++i) {
        int m = m0 + ty * TM + i;
        float4 v = make_float4(acc[i][0], acc[i][1], acc[i][2], acc[i][3]);
        *(float4*)(C + (size_t)m * N + n0 + tx * 4) = v;
    }
}

// ---------------------------------------------------------------------------
__global__ void unpack_h(const u64* __restrict__ hp, float* __restrict__ out,
                         int n) {
    int i = blockIdx.x * blockDim.x + threadIdx.x;
    if (i < n) out[i] = __uint_as_float((unsigned)hp[i]);
}

// ---------------------------------------------------------------------------
// 32 WGs/layer x 1024 thr (16 waves). Lane = row (gate*16 + col_local).
// Layers 1/2: wave wv owns k-chunk [wv*64,+64) of concat [prev-h; own-h]:
//   wv<8 -> prev-h / Wih (polled from hpX prev-feed copy),
//   wv>=8 -> own-h / Whh (polled from hp own-copy). Lane polls one element
//   into a VGPR; dot = 64x readlane-broadcast + fmac against w[64].
// Layer 0: wave wv owns own-h k [wv*32,+32) (lanes 0-31 poll own-copy) and
//   x k [2wv,2wv+1] (lanes 32-33 load seq; weights in w[32..33]).
// Publish: wave 0 lanes 0-31 compute gates redundantly (c replicated);
//   lanes 0-15 store the own-copy line, lanes 16-31 store the prev-feed
//   line (layers 0-1) — two 128B lines, one wave, same issue slot.
// ---------------------------------------------------------------------------
__global__ __launch_bounds__(NTH, 4)
void lstm_fused(const float* __restrict__ seq,
                const float* __restrict__ Wih1, const float* __restrict__ Whh1,
                const float* __restrict__ bih1, const float* __restrict__ bhh1,
                const float* __restrict__ Wih2, const float* __restrict__ Whh2,
                const float* __restrict__ bih2, const float* __restrict__ bhh2,
                const float* __restrict__ Wih3, const float* __restrict__ Whh3,
                const float* __restrict__ bih3, const float* __restrict__ bhh3,
                u64* __restrict__ hp) {
    __shared__ float part[2][NTH];      // [pb][wv*64 + row]

    const int blk   = blockIdx.x;
    const int layer = blk >> 5;
    const int g     = blk & 31;
    const int tid   = threadIdx.x;
    const int wv    = tid >> 6;          // 0..15
    const int lane  = tid & 63;          // = row (gate*16 + col_local)
    const int grow  = (lane >> 4) * HDIM + g * 16 + (lane & 15);

    const float* Wih = layer == 0 ? Wih1 : (layer == 1 ? Wih2 : Wih3);
    const float* Whh = layer == 0 ? Whh1 : (layer == 1 ? Whh2 : Whh3);
    const float* bih = layer == 0 ? bih1 : (layer == 1 ? bih2 : bih3);
    const float* bhh = layer == 0 ? bhh1 : (layer == 1 ? bhh2 : bhh3);

    // ---- 64 weight floats/lane (loop-constant indexing only) ----
    float w[64];
    #pragma unroll
    for (int m = 0; m < 64; ++m) w[m] = 0.f;
    if (layer == 0) {
        const float* wp = Whh + (size_t)grow * HDIM + wv * 32;
        #pragma unroll
        for (int i = 0; i < 8; ++i) {
            float4 v = ((const float4*)wp)[i];
            w[4*i+0]=v.x; w[4*i+1]=v.y; w[4*i+2]=v.z; w[4*i+3]=v.w;
        }
        // x weights: 2 per wave (k = 2wv, 2wv+1), all 16 waves balanced.
        w[32] = Wih[(size_t)grow * 32 + 2 * wv + 0];
        w[33] = Wih[(size_t)grow * 32 + 2 * wv + 1];
    } else {
        const float* wp = (wv < 8)
            ? Wih + (size_t)grow * HDIM + wv * 64
            : Whh + (size_t)grow * HDIM + (wv - 8) * 64;
        #pragma unroll
        for (int i = 0; i < 16; ++i) {
            float4 v = ((const float4*)wp)[i];
            w[4*i+0]=v.x; w[4*i+1]=v.y; w[4*i+2]=v.z; w[4*i+3]=v.w;
        }
    }
    #pragma unroll
    for (int m = 0; m < 64; ++m) asm volatile("" : "+v"(w[m]));

    const float brow = bih[grow] + bhh[grow];

    // hp layout: [0..3) own-copies per layer; [3..5) prev-feed copies (L0,L1).
    u64*       hpOwn   = hp + (size_t)layer * T_SEQ * HDIM;
    u64*       hpX     = hp + (size_t)3 * T_SEQ * HDIM;
    u64*       hpXOwn  = hpX + (size_t)layer * T_SEQ * HDIM;        // L0/L1
    const u64* hpPrevX = hpX + (size_t)(layer > 0 ? layer - 1 : 0) * T_SEQ * HDIM;

    float c = 0.f;   // cell state (wave 0, lanes 0..31, replicated 16/16)

    for (unsigned t = 0; t < T_SEQ; ++t) {
        const int pb = t & 1;

        // ---- per-wave poll: chunk element straight into a VGPR ----
        float hval = 0.f;
        float xval = 0.f;
        if (layer == 0) {
            if (lane < 32 && t > 0) {
                const u64* ph = hpOwn + (size_t)(t - 1) * HDIM + wv * 32 + lane;
                u64 v;
                do { v = cohLoad(ph); } while ((unsigned)(v >> 32) != t);
                hval = __uint_as_float((unsigned)v);
            }
            if (lane >= 32 && lane < 34)     // x: 2 elements per wave
                xval = seq[(size_t)t * 32 + 2 * wv + (lane - 32)];
        } else {
            if (wv < 8) {              // prev-layer h[t] via prev-feed copy
                const u64* px = hpPrevX + (size_t)t * HDIM + wv * 64 + lane;
                u64 v;
                do { v = cohLoad(px); } while ((unsigned)(v >> 32) != t + 1u);
                hval = __uint_as_float((unsigned)v);
            } else if (t > 0) {        // own h[t-1] via own-copy, tag t
                const u64* ph = hpOwn + (size_t)(t - 1) * HDIM
                              + (wv - 8) * 64 + lane;
                u64 v;
                do { v = cohLoad(ph); } while ((unsigned)(v >> 32) != t);
                hval = __uint_as_float((unsigned)v);
            }
        }

        // ---- dot: readlane broadcast + fmac, NO LDS ----
        float pe = 0.f, po = 0.f;
        if (layer == 0) {
            #pragma unroll
            for (int k = 0; k < 32; k += 2) {
                pe = fmaf(bcast(hval, k),     w[k],     pe);
                po = fmaf(bcast(hval, k + 1), w[k + 1], po);
            }
            // balanced x contribution: 2 MACs per wave
            pe = fmaf(bcast(xval, 32), w[32], pe);
            po = fmaf(bcast(xval, 33), w[33], po);
        } else {
            #pragma unroll
            for (int k = 0; k < 64; k += 2) {
                pe = fmaf(bcast(hval, k),     w[k],     pe);
                po = fmaf(bcast(hval, k + 1), w[k + 1], po);
            }
        }
        part[pb][wv * 64 + lane] = pe + po;
        __syncthreads();

        // ---- wave 0: cross-wave sum, gates, dual-copy 128B publishes ----
        if (wv == 0) {
            float tot = brow;
            #pragma unroll
            for (int wvv = 0; wvv < 16; ++wvv) tot += part[pb][wvv * 64 + lane];
            const int c16 = lane & 15;
            float ai = __shfl(tot, c16 +  0, 64);
            float af = __shfl(tot, c16 + 16, 64);
            float ag = __shfl(tot, c16 + 32, 64);
            float ao = __shfl(tot, c16 + 48, 64);
            if (lane < 32) {
                float iv = fsigmoid(ai);
                float fv = fsigmoid(af);
                float gv = ftanh(ag);
                float ov = fsigmoid(ao);
                c = fv * c + iv * gv;        // replicated lanes 0-15 / 16-31
                float h = ov * ftanh(c);
                u64 pkt = (u64)__float_as_uint(h) | ((u64)(t + 1u) << 32);
                if (lane < 16)               // own-copy: own-h pollers only
                    cohStore(hpOwn + (size_t)t * HDIM + g * 16 + lane, pkt);
                else if (layer < 2)          // prev-feed copy: next layer only
                    cohStore(hpXOwn + (size_t)t * HDIM + g * 16 + (lane - 16),
                             pkt);
            }
        }
        // Other waves roll straight into polling t+1 (no pre-dot barrier:
        // each wave consumes only its own polled registers). part[] is
        // double-buffered; writes to part[pb] recur only at t+2, after
        // barrier(t+1), which wave 0 reaches only after its tail(t) reads.
    }
}

// ---------------------------------------------------------------------------
extern "C" void kernel_launch(void* const* d_in, const int* in_sizes, int n_in,
                              void* d_out, int out_size, void* d_ws, size_t ws_size,
                              hipStream_t stream) {
    const float* seq   = (const float*)d_in[0];
    const float* W_ih1 = (const float*)d_in[1];
    const float* W_hh1 = (const float*)d_in[2];
    const float* b_ih1 = (const float*)d_in[3];
    const float* b_hh1 = (const float*)d_in[4];
    const float* W_ih2 = (const float*)d_in[5];
    const float* W_hh2 = (const float*)d_in[6];
    const float* b_ih2 = (const float*)d_in[7];
    const float* b_hh2 = (const float*)d_in[8];
    const float* W_ih3 = (const float*)d_in[9];
    const float* W_hh3 = (const float*)d_in[10];
    const float* b_ih3 = (const float*)d_in[11];
    const float* b_hh3 = (const float*)d_in[12];
    const float* W_out = (const float*)d_in[13];
    const float* b_out = (const float*)d_in[14];
    float* out = (float*)d_out;

    // Workspace: hp[3][T][512] own-copies (50.3MB) + hpX[2][T][512]
    // prev-feed copies (33.5MB); hs2 floats reuse the dead layer-0
    // packed region after the recurrence.
    u64*   hp   = (u64*)d_ws;
    float* hs2f = (float*)d_ws;
    const u64* hp2 = hp + (size_t)2 * T_SEQ * HDIM;

    hipMemsetAsync(hp, 0, (size_t)5 * T_SEQ * HDIM * sizeof(u64), stream);

    lstm_fused<<<3 * NWG_L, NTH, 0, stream>>>(
        seq, W_ih1, W_hh1, b_ih1, b_hh1, W_ih2, W_hh2, b_ih2, b_hh2,
        W_ih3, W_hh3, b_ih3, b_hh3, hp);

    const int n = T_SEQ * HDIM;
    unpack_h<<<(n + 255) / 256, 256, 0, stream>>>(hp2, hs2f, n);

    gemm_abt<64, 32, 32><<<dim3(1, T_SEQ / 64), 256, 0, stream>>>(
        hs2f, W_out, b_out, out, T_SEQ, 32, HDIM);
}